// Round 14
// baseline (198.652 us; speedup 1.0000x reference)
//
#include <hip/hip_runtime.h>

#define HH 4
#define CC 128
#define NPB 64

typedef __attribute__((ext_vector_type(8))) short short8v;   // 8 bf16
typedef __attribute__((ext_vector_type(4))) float f32x4;

static inline size_t roundup256(size_t x) { return (x + 255) & ~(size_t)255; }

static __device__ __forceinline__ unsigned short f2bf(float f) {
    unsigned int u = __float_as_uint(f);
    unsigned int r = (u + 0x7FFFu + ((u >> 16) & 1u)) >> 16;   // RNE
    return (unsigned short)r;
}

// ---------------- prep: mean + hist + Lin + gtab + pwL (logits B) + pwB -----
// Lin[bh][6] = 0.6*sum_c att*{A,B,C,D,E,F};  gtab[bh*128+c] = 0.4*att
// pwL[(bh*8+ct)*64+l][j]: B-frag for logits MFMA: lanes l<16 hold coef j(<6)
//   of channel ct*16+l, else 0.   (coefs: A,B,C,D,E,F=bsrc+bdst)
// pwB[(ct*8+kc)*64+l][j] = bf16(Wfuse[kc*32+(l>>4)*8+j][ct*16+(l&15)])
__global__ __launch_bounds__(256) void prep_kernel(
    const int* __restrict__ ei, const float* __restrict__ eattr,
    float* __restrict__ meansum, float* __restrict__ Lin,
    float* __restrict__ gtab, int* __restrict__ cnt,
    const float* __restrict__ Wsrc0, const float* __restrict__ bsrc0,
    const float* __restrict__ Wdst0, const float* __restrict__ bdst0,
    const float* __restrict__ Wedge0, const float* __restrict__ att0,
    const float* __restrict__ Wsrc1, const float* __restrict__ bsrc1,
    const float* __restrict__ Wdst1, const float* __restrict__ bdst1,
    const float* __restrict__ Wedge1, const float* __restrict__ att1,
    const float* __restrict__ Wfuse,
    unsigned short* __restrict__ pwL, unsigned short* __restrict__ pwB, int E)
{
    int tid = blockIdx.x * 256 + threadIdx.x;
    int lane = threadIdx.x & 63, wid = threadIdx.x >> 6;
    float s = 0.f;
    if (tid < E) {
        atomicAdd(&cnt[ei[E + tid]], 1);
        s = eattr[tid];
    }
    #pragma unroll
    for (int off = 32; off > 0; off >>= 1) s += __shfl_down(s, off, 64);
    __shared__ float wsum[4];
    if (lane == 0) wsum[wid] = s;
    __syncthreads();
    if (threadIdx.x == 0)
        atomicAdd(meansum, wsum[0] + wsum[1] + wsum[2] + wsum[3]);

    if (blockIdx.x < 4) {  // tid < 1024: one thread per (b,h,c)
        int b = tid >> 9;
        int hc = tid & 511;
        int c = hc & 127;
        int h = hc >> 7;
        int bh = b * 4 + h;
        const float* Ws = b ? Wsrc1 : Wsrc0;
        const float* bs = b ? bsrc1 : bsrc0;
        const float* Wd = b ? Wdst1 : Wdst0;
        const float* bd = b ? bdst1 : bdst0;
        const float* We = b ? Wedge1 : Wedge0;
        const float* at = b ? att1 : att0;
        float A = Ws[hc], B = Ws[512 + hc];
        float C = Wd[hc], D = Wd[512 + hc];
        float Ec = We[hc];
        float F = bs[hc] + bd[hc];
        float a = at[hc];
        gtab[bh * 128 + c] = 0.4f * a;
        float sa = 0.6f * a;
        float vals[6] = {sa * A, sa * B, sa * C, sa * D, sa * Ec, sa * F};
        #pragma unroll
        for (int k = 0; k < 6; ++k) {
            float v = vals[k];
            #pragma unroll
            for (int off = 32; off > 0; off >>= 1) v += __shfl_down(v, off, 64);
            vals[k] = v;
        }
        __shared__ float Ls[4][6];
        if (lane == 0) {
            #pragma unroll
            for (int k = 0; k < 6; ++k) Ls[wid][k] = vals[k];
        }
        __syncthreads();
        if (threadIdx.x < 12) {
            int w2 = threadIdx.x / 6;
            int k = threadIdx.x % 6;
            int bhg = blockIdx.x * 2 + w2;
            Lin[bhg * 6 + k] = Ls[w2 * 2][k] + Ls[w2 * 2 + 1][k];
        }
    }

    if (blockIdx.x >= 4 && blockIdx.x < 20) {  // Wfuse -> bf16 B-frags (node)
        int t2 = tid - 1024;                   // 0..4095
        int ct = t2 >> 9;
        int kc = (t2 >> 6) & 7;
        int l  = t2 & 63;
        int c = ct * 16 + (l & 15);
        int kb = kc * 32 + (l >> 4) * 8;
        unsigned short v[8];
        #pragma unroll
        for (int j = 0; j < 8; ++j)
            v[j] = f2bf(Wfuse[(kb + j) * CC + c]);
        unsigned short* dst = pwB + (size_t)t2 * 8;
        #pragma unroll
        for (int j = 0; j < 8; ++j) dst[j] = v[j];
    }

    if (blockIdx.x >= 20 && blockIdx.x < 36) {  // logits B-frags
        int t2 = tid - 5120;                    // 0..4095
        int bh = t2 >> 9;                       // 0..7
        int ct = (t2 >> 6) & 7;                 // 0..7
        int l  = t2 & 63;
        unsigned short v[8] = {0, 0, 0, 0, 0, 0, 0, 0};
        if (l < 16) {
            int b = bh >> 2, h = bh & 3;
            int c = ct * 16 + l;
            int hc = h * 128 + c;
            const float* Ws = b ? Wsrc1 : Wsrc0;
            const float* bs = b ? bsrc1 : bsrc0;
            const float* Wd = b ? Wdst1 : Wdst0;
            const float* bd = b ? bdst1 : bdst0;
            const float* We = b ? Wedge1 : Wedge0;
            v[0] = f2bf(Ws[hc]);
            v[1] = f2bf(Ws[512 + hc]);
            v[2] = f2bf(Wd[hc]);
            v[3] = f2bf(Wd[512 + hc]);
            v[4] = f2bf(We[hc]);
            v[5] = f2bf(bs[hc] + bd[hc]);
        }
        unsigned short* dst = pwL + (size_t)t2 * 8;
        #pragma unroll
        for (int j = 0; j < 8; ++j) dst[j] = v[j];
    }
}

// ---------------- scan: exclusive prefix over (cnt+1), seeds cur ------------
__global__ __launch_bounds__(1024) void scan_kernel(const int* __restrict__ cnt,
                                                    int* __restrict__ rowptr,
                                                    int* __restrict__ cur, int N) {
    const int CH = 32;
    int t = threadIdx.x;
    int base = t * CH;
    int local[CH];
    int s = 0;
    #pragma unroll
    for (int i = 0; i < CH; ++i) {
        int idx = base + i;
        int v = (idx < N) ? cnt[idx] + 1 : 0;  // +1 = self loop
        local[i] = s;
        s += v;
    }
    __shared__ int sums[1024];
    sums[t] = s;
    __syncthreads();
    for (int off = 1; off < 1024; off <<= 1) {
        int v = (t >= off) ? sums[t - off] : 0;
        __syncthreads();
        sums[t] += v;
        __syncthreads();
    }
    int excl = sums[t] - s;
    #pragma unroll
    for (int i = 0; i < CH; ++i) {
        int idx = base + i;
        if (idx < N) {
            int v = excl + local[i];
            rowptr[idx] = v;
            cur[idx] = v;
        }
    }
    if (t == 1023) rowptr[N] = excl + s;
}

// ---------------- scatter: build CSR edge records {xs,xd} + ea --------------
__global__ __launch_bounds__(256) void scatter_kernel(
    const int* __restrict__ ei, const float* __restrict__ x,
    const float* __restrict__ eattr, const float* __restrict__ meansum,
    int* __restrict__ cur, float4* __restrict__ ed4, float* __restrict__ ea1,
    int N, int E) {
    int e = blockIdx.x * 256 + threadIdx.x;
    int Etot = E + N;
    if (e >= Etot) return;
    int src, dst;
    float ea;
    if (e < E) { src = ei[e]; dst = ei[E + e]; ea = eattr[e]; }
    else       { src = e - E; dst = src; ea = meansum[0] / (float)E; }
    int pos = atomicAdd(&cur[dst], 1);
    const float2* x2 = (const float2*)x;
    float2 xs = x2[src];
    float2 xd = x2[dst];
    ed4[pos] = make_float4(xs.x, xs.y, xd.x, xd.y);
    ea1[pos] = ea;
}

// ---------------- logits via MFMA: u tiles on matrix cores ------------------
// Wave handles 64 edges, all 8 bh. A = edges [16e x 32k] (k<6 useful),
// B = pwL weights [32k x 16ch]. D: row=edge=(l>>4)*4+j, col=ch=l&15 (f32 exact).
// logit = Lin[bh].(edge,1) + sum_c gtab*|u|; p8[bh*EtotPad+e] = exp(logit).
__global__ __launch_bounds__(256) void logits_kernel(
    const float4* __restrict__ ed4,
    const float* __restrict__ ea1,
    const float* __restrict__ Lin,
    const float* __restrict__ gtab,
    const unsigned short* __restrict__ pwL,
    float* __restrict__ p8, int EtotPad)
{
    int t = threadIdx.x;
    int w = t >> 6, l = t & 63;
    int base = blockIdx.x * 256 + w * 64;
    int col = l & 15, grp = l >> 4;

    // A-frags: 4 edge tiles; only lanes grp==0 carry data (k=0..7)
    short8v a[4];
    #pragma unroll
    for (int et = 0; et < 4; ++et) {
        short8v v = {0, 0, 0, 0, 0, 0, 0, 0};
        if (grp == 0) {
            int e = base + et * 16 + col;
            float4 ev = ed4[e];
            float ea = ea1[e];
            v[0] = (short)f2bf(ev.x);
            v[1] = (short)f2bf(ev.y);
            v[2] = (short)f2bf(ev.z);
            v[3] = (short)f2bf(ev.w);
            v[4] = (short)f2bf(ea);
            v[5] = (short)f2bf(1.0f);
        }
        a[et] = v;
    }

    const short8v* pB = reinterpret_cast<const short8v*>(pwL);

    #pragma unroll
    for (int bh = 0; bh < 8; ++bh) {
        f32x4 acc[4];
        #pragma unroll
        for (int et = 0; et < 4; ++et) acc[et] = (f32x4){0.f, 0.f, 0.f, 0.f};

        #pragma unroll
        for (int ct = 0; ct < 8; ++ct) {
            short8v bfrag = pB[(bh * 8 + ct) * 64 + l];
            float g = gtab[bh * 128 + ct * 16 + col];
            #pragma unroll
            for (int et = 0; et < 4; ++et) {
                f32x4 u = __builtin_amdgcn_mfma_f32_16x16x32_bf16(
                    a[et], bfrag, (f32x4){0.f, 0.f, 0.f, 0.f}, 0, 0, 0);
                #pragma unroll
                for (int j = 0; j < 4; ++j)
                    acc[et][j] = fmaf(g, __builtin_fabsf(u[j]), acc[et][j]);
            }
        }

        const float* Lp = Lin + bh * 6;
        float l0 = Lp[0], l1 = Lp[1], l2 = Lp[2], l3 = Lp[3], l4 = Lp[4], l5 = Lp[5];
        float* plane = p8 + (size_t)bh * EtotPad;

        #pragma unroll
        for (int et = 0; et < 4; ++et) {
            float s0 = acc[et][0], s1 = acc[et][1], s2 = acc[et][2], s3 = acc[et][3];
            #pragma unroll
            for (int m = 1; m < 16; m <<= 1) {
                s0 += __shfl_xor(s0, m);
                s1 += __shfl_xor(s1, m);
                s2 += __shfl_xor(s2, m);
                s3 += __shfl_xor(s3, m);
            }
            if (col < 4) {
                float sv = (col == 0) ? s0 : (col == 1) ? s1 : (col == 2) ? s2 : s3;
                int e = base + et * 16 + grp * 4 + col;
                float4 ev = ed4[e];
                float ea = ea1[e];
                float lg = fmaf(l0, ev.x, fmaf(l1, ev.y, fmaf(l2, ev.z,
                           fmaf(l3, ev.w, fmaf(l4, ea, l5))))) + sv;
                plane[e] = __expf(lg);
            }
        }
    }
}

// ---------------- nodeS: per-node gather; stores S pre-divided by denom -----
__global__ __launch_bounds__(256) void nodeS_kernel(
    const int* __restrict__ rowptr, const float4* __restrict__ ed4,
    const float* __restrict__ p8, float* __restrict__ S, int N, int EtotPad)
{
    int t = threadIdx.x;
    int g = t >> 3, bh = t & 7;
    int n = blockIdx.x * 32 + g;
    if (n >= N) return;
    int beg = rowptr[n], end = rowptr[n + 1];
    const float* plane = p8 + (size_t)bh * EtotPad;
    float s0 = 0.f, s1 = 0.f, sb = 0.f;
    for (int i = beg; i < end; ++i) {
        float4 ed = ed4[i];
        float p = plane[i];
        s0 = fmaf(p, ed.x, s0);
        s1 = fmaf(p, ed.y, s1);
        sb += p;
    }
    float rin = 1.f / (sb + 1e-16f);
    float* Sp = S + (size_t)n * 24 + bh * 3;
    Sp[0] = s0 * rin;
    Sp[1] = s1 * rin;
    Sp[2] = sb * rin;
}

// ---------------- node: h-build (f32->bf16 LDS) + MFMA fuse GEMM ------------
__global__ __launch_bounds__(512) void node_kernel(
    const float* __restrict__ x,
    const float* __restrict__ S,
    const float* __restrict__ Wsrc0, const float* __restrict__ bsrc0,
    const float* __restrict__ bias0, const float* __restrict__ Wres0,
    const float* __restrict__ Wsrc1, const float* __restrict__ bsrc1,
    const float* __restrict__ bias1, const float* __restrict__ Wres1,
    const unsigned short* __restrict__ pwB, const float* __restrict__ bfuse,
    float* __restrict__ out, int N)
{
    __shared__ __align__(16) unsigned short hb[NPB][264];
    int t = threadIdx.x;
    int c = t & (CC - 1);
    int quarter = t >> 7;
    int n0 = blockIdx.x * NPB;

    float w00[HH], w01[HH], wb0[HH], w10[HH], w11[HH], wb1[HH];
    #pragma unroll
    for (int h = 0; h < HH; ++h) {
        w00[h] = Wsrc0[h * CC + c];
        w01[h] = Wsrc0[512 + h * CC + c];
        wb0[h] = bsrc0[h * CC + c];
        w10[h] = Wsrc1[h * CC + c];
        w11[h] = Wsrc1[512 + h * CC + c];
        wb1[h] = bsrc1[h * CC + c];
    }
    float bi0 = bias0[c], bi1 = bias1[c];
    float r00 = Wres0[c], r01 = Wres0[CC + c];
    float r10 = Wres1[c], r11 = Wres1[CC + c];

    for (int ni = quarter; ni < NPB; ni += 4) {
        int n = n0 + ni;
        if (n < N) {
            float x0 = x[2 * n], x1 = x[2 * n + 1];
            const float4* Sp4 = (const float4*)(S + (size_t)n * 24);
            float4 q0 = Sp4[0], q1 = Sp4[1], q2 = Sp4[2];
            float4 q3 = Sp4[3], q4 = Sp4[4], q5 = Sp4[5];
            float h0v, h1v;
            {
                float s0[HH] = {q0.x, q0.w, q1.z, q2.y};
                float s1[HH] = {q0.y, q1.x, q1.w, q2.z};
                float sb[HH] = {q0.z, q1.y, q2.x, q2.w};
                float acc = 0.f;
                #pragma unroll
                for (int h = 0; h < HH; ++h)
                    acc += fmaf(w00[h], s0[h], fmaf(w01[h], s1[h], wb0[h] * sb[h]));
                float o = fmaxf(acc * 0.25f + bi0, 0.f);
                h0v = o + x0 * r00 + x1 * r01;
            }
            {
                float s0[HH] = {q3.x, q3.w, q4.z, q5.y};
                float s1[HH] = {q3.y, q4.x, q4.w, q5.z};
                float sb[HH] = {q3.z, q4.y, q5.x, q5.w};
                float acc = 0.f;
                #pragma unroll
                for (int h = 0; h < HH; ++h)
                    acc += fmaf(w10[h], s0[h], fmaf(w11[h], s1[h], wb1[h] * sb[h]));
                float o = fmaxf(acc * 0.25f + bi1, 0.f);
                h1v = o + x0 * r10 + x1 * r11;
            }
            hb[ni][c] = f2bf(h0v);
            hb[ni][CC + c] = f2bf(h1v);
        }
    }
    __syncthreads();

    int w = t >> 6;
    int l = t & 63;
    int nt = w & 3;
    int cthalf = w >> 2;
    int row = nt * 16 + (l & 15);

    short8v a[8];
    #pragma unroll
    for (int kc = 0; kc < 8; ++kc)
        a[kc] = *reinterpret_cast<const short8v*>(&hb[row][kc * 32 + (l >> 4) * 8]);

    const short8v* pB = reinterpret_cast<const short8v*>(pwB);
    #pragma unroll
    for (int ci = 0; ci < 4; ++ci) {
        int ct = cthalf * 4 + ci;
        f32x4 acc = {0.f, 0.f, 0.f, 0.f};
        #pragma unroll
        for (int kc = 0; kc < 8; ++kc) {
            short8v b = pB[(ct * 8 + kc) * 64 + l];
            acc = __builtin_amdgcn_mfma_f32_16x16x32_bf16(a[kc], b, acc, 0, 0, 0);
        }
        int ch = ct * 16 + (l & 15);
        float bi = bfuse[ch];
        #pragma unroll
        for (int j = 0; j < 4; ++j) {
            int n = n0 + nt * 16 + (l >> 4) * 4 + j;
            if (n < N) out[(size_t)n * CC + ch] = fmaxf(acc[j] + bi, 0.f);
        }
    }
}

extern "C" void kernel_launch(void* const* d_in, const int* in_sizes, int n_in,
                              void* d_out, int out_size, void* d_ws, size_t ws_size,
                              hipStream_t stream) {
    const float* x      = (const float*)d_in[0];
    const int*   ei     = (const int*)d_in[1];
    const float* eattr  = (const float*)d_in[2];
    const float* Wsrc0  = (const float*)d_in[3];
    const float* bsrc0  = (const float*)d_in[4];
    const float* Wdst0  = (const float*)d_in[5];
    const float* bdst0  = (const float*)d_in[6];
    const float* Wedge0 = (const float*)d_in[7];
    const float* att0   = (const float*)d_in[8];
    const float* bias0  = (const float*)d_in[9];
    const float* Wres0  = (const float*)d_in[10];
    const float* Wsrc1  = (const float*)d_in[11];
    const float* bsrc1  = (const float*)d_in[12];
    const float* Wdst1  = (const float*)d_in[13];
    const float* bdst1  = (const float*)d_in[14];
    const float* Wedge1 = (const float*)d_in[15];
    const float* att1   = (const float*)d_in[16];
    const float* bias1  = (const float*)d_in[17];
    const float* Wres1  = (const float*)d_in[18];
    const float* Wfuse  = (const float*)d_in[19];
    const float* bfuse  = (const float*)d_in[20];
    float* out = (float*)d_out;

    int N = in_sizes[0] / 2;   // x is (N,2)
    int E = in_sizes[1] / 2;   // edge_index is (2,E)
    int Etot = E + N;
    int EtotPad = (Etot + 511) & ~511;

    // workspace layout; zero region = meansum(0..4) + cnt
    size_t off = 0;
    float* meansum = (float*)((char*)d_ws + off);  off += 256;
    int*   cnt     = (int*)((char*)d_ws + off);    off += roundup256((size_t)N * sizeof(int));
    size_t zero_bytes = off;
    float* Lin     = (float*)((char*)d_ws + off);  off += 256;
    float* gtab    = (float*)((char*)d_ws + off);  off += roundup256(1024 * sizeof(float));
    int*   cur     = (int*)((char*)d_ws + off);    off += roundup256((size_t)N * sizeof(int));
    int*   rowptr  = (int*)((char*)d_ws + off);    off += roundup256((size_t)(N + 1) * sizeof(int));
    unsigned short* pwB = (unsigned short*)((char*)d_ws + off);
                                                   off += roundup256(4096 * 8 * sizeof(unsigned short));
    unsigned short* pwL = (unsigned short*)((char*)d_ws + off);
                                                   off += roundup256(4096 * 8 * sizeof(unsigned short));
    float4* ed4    = (float4*)((char*)d_ws + off); off += roundup256((size_t)EtotPad * sizeof(float4));
    float* ea1     = (float*)((char*)d_ws + off);  off += roundup256((size_t)EtotPad * sizeof(float));
    float* p8      = (float*)((char*)d_ws + off);  off += roundup256((size_t)EtotPad * 8 * sizeof(float));
    float* S       = (float*)((char*)d_ws + off);  off += roundup256((size_t)24 * N * sizeof(float));

    hipMemsetAsync(d_ws, 0, zero_bytes, stream);

    prep_kernel<<<(E + 255) / 256, 256, 0, stream>>>(
        ei, eattr, meansum, Lin, gtab, cnt,
        Wsrc0, bsrc0, Wdst0, bdst0, Wedge0, att0,
        Wsrc1, bsrc1, Wdst1, bdst1, Wedge1, att1,
        Wfuse, pwL, pwB, E);

    scan_kernel<<<1, 1024, 0, stream>>>(cnt, rowptr, cur, N);

    scatter_kernel<<<(Etot + 255) / 256, 256, 0, stream>>>(
        ei, x, eattr, meansum, cur, ed4, ea1, N, E);

    logits_kernel<<<EtotPad / 256, 256, 0, stream>>>(
        ed4, ea1, Lin, gtab, pwL, p8, EtotPad);

    nodeS_kernel<<<(N + 31) / 32, 256, 0, stream>>>(rowptr, ed4, p8, S, N, EtotPad);

    node_kernel<<<(N + NPB - 1) / NPB, 512, 0, stream>>>(
        x, S,
        Wsrc0, bsrc0, bias0, Wres0,
        Wsrc1, bsrc1, bias1, Wres1,
        pwB, bfuse, out, N);
}

// Round 15
// 187.942 us; speedup vs baseline: 1.0570x; 1.0570x over previous
//
#include <hip/hip_runtime.h>

#define HH 4
#define CC 128
#define NPB 64

typedef __attribute__((ext_vector_type(8))) short short8v;   // 8 bf16
typedef __attribute__((ext_vector_type(4))) float f32x4;

static inline size_t roundup256(size_t x) { return (x + 255) & ~(size_t)255; }

static __device__ __forceinline__ unsigned short f2bf(float f) {
    unsigned int u = __float_as_uint(f);
    unsigned int r = (u + 0x7FFFu + ((u >> 16) & 1u)) >> 16;   // RNE
    return (unsigned short)r;
}

// ---------------- prep: mean + hist + Lin + gtab + pwL (logits B) + pwB -----
__global__ __launch_bounds__(256) void prep_kernel(
    const int* __restrict__ ei, const float* __restrict__ eattr,
    float* __restrict__ meansum, float* __restrict__ Lin,
    float* __restrict__ gtab, int* __restrict__ cnt,
    const float* __restrict__ Wsrc0, const float* __restrict__ bsrc0,
    const float* __restrict__ Wdst0, const float* __restrict__ bdst0,
    const float* __restrict__ Wedge0, const float* __restrict__ att0,
    const float* __restrict__ Wsrc1, const float* __restrict__ bsrc1,
    const float* __restrict__ Wdst1, const float* __restrict__ bdst1,
    const float* __restrict__ Wedge1, const float* __restrict__ att1,
    const float* __restrict__ Wfuse,
    unsigned short* __restrict__ pwL, unsigned short* __restrict__ pwB, int E)
{
    int tid = blockIdx.x * 256 + threadIdx.x;
    int lane = threadIdx.x & 63, wid = threadIdx.x >> 6;
    float s = 0.f;
    if (tid < E) {
        atomicAdd(&cnt[ei[E + tid]], 1);
        s = eattr[tid];
    }
    #pragma unroll
    for (int off = 32; off > 0; off >>= 1) s += __shfl_down(s, off, 64);
    __shared__ float wsum[4];
    if (lane == 0) wsum[wid] = s;
    __syncthreads();
    if (threadIdx.x == 0)
        atomicAdd(meansum, wsum[0] + wsum[1] + wsum[2] + wsum[3]);

    if (blockIdx.x < 4) {  // tid < 1024: one thread per (b,h,c)
        int b = tid >> 9;
        int hc = tid & 511;
        int c = hc & 127;
        int h = hc >> 7;
        int bh = b * 4 + h;
        const float* Ws = b ? Wsrc1 : Wsrc0;
        const float* bs = b ? bsrc1 : bsrc0;
        const float* Wd = b ? Wdst1 : Wdst0;
        const float* bd = b ? bdst1 : bdst0;
        const float* We = b ? Wedge1 : Wedge0;
        const float* at = b ? att1 : att0;
        float A = Ws[hc], B = Ws[512 + hc];
        float C = Wd[hc], D = Wd[512 + hc];
        float Ec = We[hc];
        float F = bs[hc] + bd[hc];
        float a = at[hc];
        gtab[bh * 128 + c] = 0.4f * a;
        float sa = 0.6f * a;
        float vals[6] = {sa * A, sa * B, sa * C, sa * D, sa * Ec, sa * F};
        #pragma unroll
        for (int k = 0; k < 6; ++k) {
            float v = vals[k];
            #pragma unroll
            for (int off = 32; off > 0; off >>= 1) v += __shfl_down(v, off, 64);
            vals[k] = v;
        }
        __shared__ float Ls[4][6];
        if (lane == 0) {
            #pragma unroll
            for (int k = 0; k < 6; ++k) Ls[wid][k] = vals[k];
        }
        __syncthreads();
        if (threadIdx.x < 12) {
            int w2 = threadIdx.x / 6;
            int k = threadIdx.x % 6;
            int bhg = blockIdx.x * 2 + w2;
            Lin[bhg * 6 + k] = Ls[w2 * 2][k] + Ls[w2 * 2 + 1][k];
        }
    }

    if (blockIdx.x >= 4 && blockIdx.x < 20) {  // Wfuse -> bf16 B-frags (node)
        int t2 = tid - 1024;                   // 0..4095
        int ct = t2 >> 9;
        int kc = (t2 >> 6) & 7;
        int l  = t2 & 63;
        int c = ct * 16 + (l & 15);
        int kb = kc * 32 + (l >> 4) * 8;
        unsigned short v[8];
        #pragma unroll
        for (int j = 0; j < 8; ++j)
            v[j] = f2bf(Wfuse[(kb + j) * CC + c]);
        unsigned short* dst = pwB + (size_t)t2 * 8;
        #pragma unroll
        for (int j = 0; j < 8; ++j) dst[j] = v[j];
    }

    if (blockIdx.x >= 20 && blockIdx.x < 36) {  // logits B-frags
        int t2 = tid - 5120;                    // 0..4095
        int bh = t2 >> 9;                       // 0..7
        int ct = (t2 >> 6) & 7;                 // 0..7
        int l  = t2 & 63;
        unsigned short v[8] = {0, 0, 0, 0, 0, 0, 0, 0};
        if (l < 16) {
            int b = bh >> 2, h = bh & 3;
            int c = ct * 16 + l;
            int hc = h * 128 + c;
            const float* Ws = b ? Wsrc1 : Wsrc0;
            const float* bs = b ? bsrc1 : bsrc0;
            const float* Wd = b ? Wdst1 : Wdst0;
            const float* bd = b ? bdst1 : bdst0;
            const float* We = b ? Wedge1 : Wedge0;
            v[0] = f2bf(Ws[hc]);
            v[1] = f2bf(Ws[512 + hc]);
            v[2] = f2bf(Wd[hc]);
            v[3] = f2bf(Wd[512 + hc]);
            v[4] = f2bf(We[hc]);
            v[5] = f2bf(bs[hc] + bd[hc]);
        }
        unsigned short* dst = pwL + (size_t)t2 * 8;
        #pragma unroll
        for (int j = 0; j < 8; ++j) dst[j] = v[j];
    }
}

// ---------------- scan: exclusive prefix over (cnt+1), seeds cur ------------
__global__ __launch_bounds__(1024) void scan_kernel(const int* __restrict__ cnt,
                                                    int* __restrict__ rowptr,
                                                    int* __restrict__ cur, int N) {
    const int CH = 32;
    int t = threadIdx.x;
    int base = t * CH;
    int local[CH];
    int s = 0;
    #pragma unroll
    for (int i = 0; i < CH; ++i) {
        int idx = base + i;
        int v = (idx < N) ? cnt[idx] + 1 : 0;  // +1 = self loop
        local[i] = s;
        s += v;
    }
    __shared__ int sums[1024];
    sums[t] = s;
    __syncthreads();
    for (int off = 1; off < 1024; off <<= 1) {
        int v = (t >= off) ? sums[t - off] : 0;
        __syncthreads();
        sums[t] += v;
        __syncthreads();
    }
    int excl = sums[t] - s;
    #pragma unroll
    for (int i = 0; i < CH; ++i) {
        int idx = base + i;
        if (idx < N) {
            int v = excl + local[i];
            rowptr[idx] = v;
            cur[idx] = v;
        }
    }
    if (t == 1023) rowptr[N] = excl + s;
}

// ---------------- scatter: build CSR edge records {xs,xd} + ea --------------
__global__ __launch_bounds__(256) void scatter_kernel(
    const int* __restrict__ ei, const float* __restrict__ x,
    const float* __restrict__ eattr, const float* __restrict__ meansum,
    int* __restrict__ cur, float4* __restrict__ ed4, float* __restrict__ ea1,
    int N, int E) {
    int e = blockIdx.x * 256 + threadIdx.x;
    int Etot = E + N;
    if (e >= Etot) return;
    int src, dst;
    float ea;
    if (e < E) { src = ei[e]; dst = ei[E + e]; ea = eattr[e]; }
    else       { src = e - E; dst = src; ea = meansum[0] / (float)E; }
    int pos = atomicAdd(&cur[dst], 1);
    const float2* x2 = (const float2*)x;
    float2 xs = x2[src];
    float2 xd = x2[dst];
    ed4[pos] = make_float4(xs.x, xs.y, xd.x, xd.y);
    ea1[pos] = ea;
}

// ---------------- logits via MFMA, bh-pair split for occupancy --------------
// grid = 4 bh-pairs x nchunks; block = 2 bh x 256 edges (wave: 64 edges).
// A = edges [16e x 32k] (k<6 used), B = pwL [32k x 16ch].
// D: row=edge=(l>>4)*4+j, col=ch=l&15 (f32 exact).
__global__ __launch_bounds__(256, 4) void logits_kernel(
    const float4* __restrict__ ed4,
    const float* __restrict__ ea1,
    const float* __restrict__ Lin,
    const float* __restrict__ gtab,
    const unsigned short* __restrict__ pwL,
    float* __restrict__ p8, int EtotPad, int nchunks)
{
    int blk = blockIdx.x;
    int bhp = blk / nchunks;        // 0..3  (bh pair)
    int chunk = blk - bhp * nchunks;
    int t = threadIdx.x;
    int w = t >> 6, l = t & 63;
    int base = chunk * 256 + w * 64;
    int col = l & 15, grp = l >> 4;

    // A-frags: 4 edge tiles; only lanes grp==0 carry data (k=0..7)
    short8v a[4];
    #pragma unroll
    for (int et = 0; et < 4; ++et) {
        short8v v = {0, 0, 0, 0, 0, 0, 0, 0};
        if (grp == 0) {
            int e = base + et * 16 + col;
            float4 ev = ed4[e];
            float ea = ea1[e];
            v[0] = (short)f2bf(ev.x);
            v[1] = (short)f2bf(ev.y);
            v[2] = (short)f2bf(ev.z);
            v[3] = (short)f2bf(ev.w);
            v[4] = (short)f2bf(ea);
            v[5] = (short)f2bf(1.0f);
        }
        a[et] = v;
    }

    const short8v* pB = reinterpret_cast<const short8v*>(pwL);

    #pragma unroll
    for (int bi = 0; bi < 2; ++bi) {
        int bh = bhp * 2 + bi;
        f32x4 acc[4];
        #pragma unroll
        for (int et = 0; et < 4; ++et) acc[et] = (f32x4){0.f, 0.f, 0.f, 0.f};

        #pragma unroll
        for (int ct = 0; ct < 8; ++ct) {
            short8v bfrag = pB[(bh * 8 + ct) * 64 + l];
            float g = gtab[bh * 128 + ct * 16 + col];
            #pragma unroll
            for (int et = 0; et < 4; ++et) {
                f32x4 u = __builtin_amdgcn_mfma_f32_16x16x32_bf16(
                    a[et], bfrag, (f32x4){0.f, 0.f, 0.f, 0.f}, 0, 0, 0);
                #pragma unroll
                for (int j = 0; j < 4; ++j)
                    acc[et][j] = fmaf(g, __builtin_fabsf(u[j]), acc[et][j]);
            }
        }

        const float* Lp = Lin + bh * 6;
        float l0 = Lp[0], l1 = Lp[1], l2 = Lp[2], l3 = Lp[3], l4 = Lp[4], l5 = Lp[5];
        float* plane = p8 + (size_t)bh * EtotPad;

        #pragma unroll
        for (int et = 0; et < 4; ++et) {
            float s0 = acc[et][0], s1 = acc[et][1], s2 = acc[et][2], s3 = acc[et][3];
            #pragma unroll
            for (int m = 1; m < 16; m <<= 1) {
                s0 += __shfl_xor(s0, m);
                s1 += __shfl_xor(s1, m);
                s2 += __shfl_xor(s2, m);
                s3 += __shfl_xor(s3, m);
            }
            if (col < 4) {
                float sv = (col == 0) ? s0 : (col == 1) ? s1 : (col == 2) ? s2 : s3;
                int e = base + et * 16 + grp * 4 + col;
                float4 ev = ed4[e];
                float ea = ea1[e];
                float lg = fmaf(l0, ev.x, fmaf(l1, ev.y, fmaf(l2, ev.z,
                           fmaf(l3, ev.w, fmaf(l4, ea, l5))))) + sv;
                plane[e] = __expf(lg);
            }
        }
    }
}

// ---------------- nodeS: per-node gather; stores S pre-divided by denom -----
__global__ __launch_bounds__(256) void nodeS_kernel(
    const int* __restrict__ rowptr, const float4* __restrict__ ed4,
    const float* __restrict__ p8, float* __restrict__ S, int N, int EtotPad)
{
    int t = threadIdx.x;
    int g = t >> 3, bh = t & 7;
    int n = blockIdx.x * 32 + g;
    if (n >= N) return;
    int beg = rowptr[n], end = rowptr[n + 1];
    const float* plane = p8 + (size_t)bh * EtotPad;
    float s0 = 0.f, s1 = 0.f, sb = 0.f;
    for (int i = beg; i < end; ++i) {
        float4 ed = ed4[i];
        float p = plane[i];
        s0 = fmaf(p, ed.x, s0);
        s1 = fmaf(p, ed.y, s1);
        sb += p;
    }
    float rin = 1.f / (sb + 1e-16f);
    float* Sp = S + (size_t)n * 24 + bh * 3;
    Sp[0] = s0 * rin;
    Sp[1] = s1 * rin;
    Sp[2] = sb * rin;
}

// ---------------- node: h-build (f32->bf16 LDS) + MFMA fuse GEMM ------------
__global__ __launch_bounds__(512) void node_kernel(
    const float* __restrict__ x,
    const float* __restrict__ S,
    const float* __restrict__ Wsrc0, const float* __restrict__ bsrc0,
    const float* __restrict__ bias0, const float* __restrict__ Wres0,
    const float* __restrict__ Wsrc1, const float* __restrict__ bsrc1,
    const float* __restrict__ bias1, const float* __restrict__ Wres1,
    const unsigned short* __restrict__ pwB, const float* __restrict__ bfuse,
    float* __restrict__ out, int N)
{
    __shared__ __align__(16) unsigned short hb[NPB][264];
    int t = threadIdx.x;
    int c = t & (CC - 1);
    int quarter = t >> 7;
    int n0 = blockIdx.x * NPB;

    float w00[HH], w01[HH], wb0[HH], w10[HH], w11[HH], wb1[HH];
    #pragma unroll
    for (int h = 0; h < HH; ++h) {
        w00[h] = Wsrc0[h * CC + c];
        w01[h] = Wsrc0[512 + h * CC + c];
        wb0[h] = bsrc0[h * CC + c];
        w10[h] = Wsrc1[h * CC + c];
        w11[h] = Wsrc1[512 + h * CC + c];
        wb1[h] = bsrc1[h * CC + c];
    }
    float bi0 = bias0[c], bi1 = bias1[c];
    float r00 = Wres0[c], r01 = Wres0[CC + c];
    float r10 = Wres1[c], r11 = Wres1[CC + c];

    for (int ni = quarter; ni < NPB; ni += 4) {
        int n = n0 + ni;
        if (n < N) {
            float x0 = x[2 * n], x1 = x[2 * n + 1];
            const float4* Sp4 = (const float4*)(S + (size_t)n * 24);
            float4 q0 = Sp4[0], q1 = Sp4[1], q2 = Sp4[2];
            float4 q3 = Sp4[3], q4 = Sp4[4], q5 = Sp4[5];
            float h0v, h1v;
            {
                float s0[HH] = {q0.x, q0.w, q1.z, q2.y};
                float s1[HH] = {q0.y, q1.x, q1.w, q2.z};
                float sb[HH] = {q0.z, q1.y, q2.x, q2.w};
                float acc = 0.f;
                #pragma unroll
                for (int h = 0; h < HH; ++h)
                    acc += fmaf(w00[h], s0[h], fmaf(w01[h], s1[h], wb0[h] * sb[h]));
                float o = fmaxf(acc * 0.25f + bi0, 0.f);
                h0v = o + x0 * r00 + x1 * r01;
            }
            {
                float s0[HH] = {q3.x, q3.w, q4.z, q5.y};
                float s1[HH] = {q3.y, q4.x, q4.w, q5.z};
                float sb[HH] = {q3.z, q4.y, q5.x, q5.w};
                float acc = 0.f;
                #pragma unroll
                for (int h = 0; h < HH; ++h)
                    acc += fmaf(w10[h], s0[h], fmaf(w11[h], s1[h], wb1[h] * sb[h]));
                float o = fmaxf(acc * 0.25f + bi1, 0.f);
                h1v = o + x0 * r10 + x1 * r11;
            }
            hb[ni][c] = f2bf(h0v);
            hb[ni][CC + c] = f2bf(h1v);
        }
    }
    __syncthreads();

    int w = t >> 6;
    int l = t & 63;
    int nt = w & 3;
    int cthalf = w >> 2;
    int row = nt * 16 + (l & 15);

    short8v a[8];
    #pragma unroll
    for (int kc = 0; kc < 8; ++kc)
        a[kc] = *reinterpret_cast<const short8v*>(&hb[row][kc * 32 + (l >> 4) * 8]);

    const short8v* pB = reinterpret_cast<const short8v*>(pwB);
    #pragma unroll
    for (int ci = 0; ci < 4; ++ci) {
        int ct = cthalf * 4 + ci;
        f32x4 acc = {0.f, 0.f, 0.f, 0.f};
        #pragma unroll
        for (int kc = 0; kc < 8; ++kc) {
            short8v b = pB[(ct * 8 + kc) * 64 + l];
            acc = __builtin_amdgcn_mfma_f32_16x16x32_bf16(a[kc], b, acc, 0, 0, 0);
        }
        int ch = ct * 16 + (l & 15);
        float bi = bfuse[ch];
        #pragma unroll
        for (int j = 0; j < 4; ++j) {
            int n = n0 + nt * 16 + (l >> 4) * 4 + j;
            if (n < N) out[(size_t)n * CC + ch] = fmaxf(acc[j] + bi, 0.f);
        }
    }
}

extern "C" void kernel_launch(void* const* d_in, const int* in_sizes, int n_in,
                              void* d_out, int out_size, void* d_ws, size_t ws_size,
                              hipStream_t stream) {
    const float* x      = (const float*)d_in[0];
    const int*   ei     = (const int*)d_in[1];
    const float* eattr  = (const float*)d_in[2];
    const float* Wsrc0  = (const float*)d_in[3];
    const float* bsrc0  = (const float*)d_in[4];
    const float* Wdst0  = (const float*)d_in[5];
    const float* bdst0  = (const float*)d_in[6];
    const float* Wedge0 = (const float*)d_in[7];
    const float* att0   = (const float*)d_in[8];
    const float* bias0  = (const float*)d_in[9];
    const float* Wres0  = (const float*)d_in[10];
    const float* Wsrc1  = (const float*)d_in[11];
    const float* bsrc1  = (const float*)d_in[12];
    const float* Wdst1  = (const float*)d_in[13];
    const float* bdst1  = (const float*)d_in[14];
    const float* Wedge1 = (const float*)d_in[15];
    const float* att1   = (const float*)d_in[16];
    const float* bias1  = (const float*)d_in[17];
    const float* Wres1  = (const float*)d_in[18];
    const float* Wfuse  = (const float*)d_in[19];
    const float* bfuse  = (const float*)d_in[20];
    float* out = (float*)d_out;

    int N = in_sizes[0] / 2;   // x is (N,2)
    int E = in_sizes[1] / 2;   // edge_index is (2,E)
    int Etot = E + N;
    int EtotPad = (Etot + 511) & ~511;

    // workspace layout; zero region = meansum(0..4) + cnt
    size_t off = 0;
    float* meansum = (float*)((char*)d_ws + off);  off += 256;
    int*   cnt     = (int*)((char*)d_ws + off);    off += roundup256((size_t)N * sizeof(int));
    size_t zero_bytes = off;
    float* Lin     = (float*)((char*)d_ws + off);  off += 256;
    float* gtab    = (float*)((char*)d_ws + off);  off += roundup256(1024 * sizeof(float));
    int*   cur     = (int*)((char*)d_ws + off);    off += roundup256((size_t)N * sizeof(int));
    int*   rowptr  = (int*)((char*)d_ws + off);    off += roundup256((size_t)(N + 1) * sizeof(int));
    unsigned short* pwB = (unsigned short*)((char*)d_ws + off);
                                                   off += roundup256(4096 * 8 * sizeof(unsigned short));
    unsigned short* pwL = (unsigned short*)((char*)d_ws + off);
                                                   off += roundup256(4096 * 8 * sizeof(unsigned short));
    float4* ed4    = (float4*)((char*)d_ws + off); off += roundup256((size_t)EtotPad * sizeof(float4));
    float* ea1     = (float*)((char*)d_ws + off);  off += roundup256((size_t)EtotPad * sizeof(float));
    float* p8      = (float*)((char*)d_ws + off);  off += roundup256((size_t)EtotPad * 8 * sizeof(float));
    float* S       = (float*)((char*)d_ws + off);  off += roundup256((size_t)24 * N * sizeof(float));

    hipMemsetAsync(d_ws, 0, zero_bytes, stream);

    prep_kernel<<<(E + 255) / 256, 256, 0, stream>>>(
        ei, eattr, meansum, Lin, gtab, cnt,
        Wsrc0, bsrc0, Wdst0, bdst0, Wedge0, att0,
        Wsrc1, bsrc1, Wdst1, bdst1, Wedge1, att1,
        Wfuse, pwL, pwB, E);

    scan_kernel<<<1, 1024, 0, stream>>>(cnt, rowptr, cur, N);

    scatter_kernel<<<(Etot + 255) / 256, 256, 0, stream>>>(
        ei, x, eattr, meansum, cur, ed4, ea1, N, E);

    int nchunks = EtotPad / 256;
    logits_kernel<<<4 * nchunks, 256, 0, stream>>>(
        ed4, ea1, Lin, gtab, pwL, p8, EtotPad, nchunks);

    nodeS_kernel<<<(N + 31) / 32, 256, 0, stream>>>(rowptr, ed4, p8, S, N, EtotPad);

    node_kernel<<<(N + NPB - 1) / NPB, 512, 0, stream>>>(
        x, S,
        Wsrc0, bsrc0, bias0, Wres0,
        Wsrc1, bsrc1, bias1, Wres1,
        pwB, bfuse, out, N);
}

// Round 16
// 182.558 us; speedup vs baseline: 1.0882x; 1.0295x over previous
//
#include <hip/hip_runtime.h>

#define HH 4
#define CC 128
#define NPB 64

typedef __attribute__((ext_vector_type(8))) short short8v;   // 8 bf16
typedef __attribute__((ext_vector_type(4))) float f32x4;
typedef _Float16 v2h __attribute__((ext_vector_type(2)));

static inline size_t roundup256(size_t x) { return (x + 255) & ~(size_t)255; }

static __device__ __forceinline__ unsigned short f2bf(float f) {
    unsigned int u = __float_as_uint(f);
    unsigned int r = (u + 0x7FFFu + ((u >> 16) & 1u)) >> 16;   // RNE
    return (unsigned short)r;
}
static __device__ __forceinline__ v2h bch(unsigned int u) {
    v2h r;
    __builtin_memcpy(&r, &u, 4);
    return r;
}
static __device__ __forceinline__ unsigned int pkh(float a, float b) {
    v2h h = {(_Float16)a, (_Float16)b};
    unsigned int u;
    __builtin_memcpy(&u, &h, 4);
    return u;
}
#if __has_builtin(__builtin_amdgcn_fdot2)
#define FDOT2(a, b, c) __builtin_amdgcn_fdot2((a), (b), (c), false)
#else
#define FDOT2(a, b, c) \
    fmaf((float)(a).x, (float)(b).x, fmaf((float)(a).y, (float)(b).y, (c)))
#endif

// ---------------- prep: mean + hist + Lin + pwD (dot2 weights) + pwB --------
// pwD[bh*128+c] = uint4{ pk(A,B), pk(C,D), pk(E,F), bits(0.4*att) }
// Lin[bh][6] = 0.6*sum_c att*{A,B,C,D,E,F}
// pwB[(ct*8+kc)*64+l][j] = bf16(Wfuse[kc*32+(l>>4)*8+j][ct*16+(l&15)])
__global__ __launch_bounds__(256) void prep_kernel(
    const int* __restrict__ ei, const float* __restrict__ eattr,
    float* __restrict__ meansum, float* __restrict__ Lin, int* __restrict__ cnt,
    const float* __restrict__ Wsrc0, const float* __restrict__ bsrc0,
    const float* __restrict__ Wdst0, const float* __restrict__ bdst0,
    const float* __restrict__ Wedge0, const float* __restrict__ att0,
    const float* __restrict__ Wsrc1, const float* __restrict__ bsrc1,
    const float* __restrict__ Wdst1, const float* __restrict__ bdst1,
    const float* __restrict__ Wedge1, const float* __restrict__ att1,
    const float* __restrict__ Wfuse,
    uint4* __restrict__ pwD, unsigned short* __restrict__ pwB, int E)
{
    int tid = blockIdx.x * 256 + threadIdx.x;
    int lane = threadIdx.x & 63, wid = threadIdx.x >> 6;
    float s = 0.f;
    if (tid < E) {
        atomicAdd(&cnt[ei[E + tid]], 1);
        s = eattr[tid];
    }
    #pragma unroll
    for (int off = 32; off > 0; off >>= 1) s += __shfl_down(s, off, 64);
    __shared__ float wsum[4];
    if (lane == 0) wsum[wid] = s;
    __syncthreads();
    if (threadIdx.x == 0)
        atomicAdd(meansum, wsum[0] + wsum[1] + wsum[2] + wsum[3]);

    if (blockIdx.x < 4) {  // tid < 1024: one thread per (b,h,c)
        int b = tid >> 9;
        int hc = tid & 511;
        int c = hc & 127;
        int h = hc >> 7;
        int bh = b * 4 + h;
        const float* Ws = b ? Wsrc1 : Wsrc0;
        const float* bs = b ? bsrc1 : bsrc0;
        const float* Wd = b ? Wdst1 : Wdst0;
        const float* bd = b ? bdst1 : bdst0;
        const float* We = b ? Wedge1 : Wedge0;
        const float* at = b ? att1 : att0;
        float A = Ws[hc], B = Ws[512 + hc];
        float C = Wd[hc], D = Wd[512 + hc];
        float Ec = We[hc];
        float F = bs[hc] + bd[hc];
        float a = at[hc];
        pwD[bh * 128 + c] = make_uint4(pkh(A, B), pkh(C, D), pkh(Ec, F),
                                       __float_as_uint(0.4f * a));
        float sa = 0.6f * a;
        float vals[6] = {sa * A, sa * B, sa * C, sa * D, sa * Ec, sa * F};
        #pragma unroll
        for (int k = 0; k < 6; ++k) {
            float v = vals[k];
            #pragma unroll
            for (int off = 32; off > 0; off >>= 1) v += __shfl_down(v, off, 64);
            vals[k] = v;
        }
        __shared__ float Ls[4][6];
        if (lane == 0) {
            #pragma unroll
            for (int k = 0; k < 6; ++k) Ls[wid][k] = vals[k];
        }
        __syncthreads();
        if (threadIdx.x < 12) {
            int w2 = threadIdx.x / 6;
            int k = threadIdx.x % 6;
            int bhg = blockIdx.x * 2 + w2;
            Lin[bhg * 6 + k] = Ls[w2 * 2][k] + Ls[w2 * 2 + 1][k];
        }
    }

    if (blockIdx.x >= 4 && blockIdx.x < 20) {  // Wfuse -> bf16 B-frags (node)
        int t2 = tid - 1024;                   // 0..4095
        int ct = t2 >> 9;
        int kc = (t2 >> 6) & 7;
        int l  = t2 & 63;
        int c = ct * 16 + (l & 15);
        int kb = kc * 32 + (l >> 4) * 8;
        unsigned short v[8];
        #pragma unroll
        for (int j = 0; j < 8; ++j)
            v[j] = f2bf(Wfuse[(kb + j) * CC + c]);
        unsigned short* dst = pwB + (size_t)t2 * 8;
        #pragma unroll
        for (int j = 0; j < 8; ++j) dst[j] = v[j];
    }
}

// ---------------- scan: exclusive prefix over (cnt+1), seeds cur ------------
__global__ __launch_bounds__(1024) void scan_kernel(const int* __restrict__ cnt,
                                                    int* __restrict__ rowptr,
                                                    int* __restrict__ cur, int N) {
    const int CH = 32;
    int t = threadIdx.x;
    int base = t * CH;
    int local[CH];
    int s = 0;
    #pragma unroll
    for (int i = 0; i < CH; ++i) {
        int idx = base + i;
        int v = (idx < N) ? cnt[idx] + 1 : 0;  // +1 = self loop
        local[i] = s;
        s += v;
    }
    __shared__ int sums[1024];
    sums[t] = s;
    __syncthreads();
    for (int off = 1; off < 1024; off <<= 1) {
        int v = (t >= off) ? sums[t - off] : 0;
        __syncthreads();
        sums[t] += v;
        __syncthreads();
    }
    int excl = sums[t] - s;
    #pragma unroll
    for (int i = 0; i < CH; ++i) {
        int idx = base + i;
        if (idx < N) {
            int v = excl + local[i];
            rowptr[idx] = v;
            cur[idx] = v;
        }
    }
    if (t == 1023) rowptr[N] = excl + s;
}

// ---------------- scatter: CSR edge records {xs,xd} f32 + fp16 pack ---------
__global__ __launch_bounds__(256) void scatter_kernel(
    const int* __restrict__ ei, const float* __restrict__ x,
    const float* __restrict__ eattr, const float* __restrict__ meansum,
    int* __restrict__ cur, float4* __restrict__ ed4, uint4* __restrict__ eh4,
    int N, int E) {
    int e = blockIdx.x * 256 + threadIdx.x;
    int Etot = E + N;
    if (e >= Etot) return;
    int src, dst;
    float ea;
    if (e < E) { src = ei[e]; dst = ei[E + e]; ea = eattr[e]; }
    else       { src = e - E; dst = src; ea = meansum[0] / (float)E; }
    int pos = atomicAdd(&cur[dst], 1);
    const float2* x2 = (const float2*)x;
    float2 xs = x2[src];
    float2 xd = x2[dst];
    ed4[pos] = make_float4(xs.x, xs.y, xd.x, xd.y);
    eh4[pos] = make_uint4(pkh(xs.x, xs.y), pkh(xd.x, xd.y), pkh(ea, 1.f), 0);
}

// ---------------- logits: fp16 dot2, 8-phase bh split, 2 edges/lane ---------
// u = AB.(xs0,xs1) + CD.(xd0,xd1) + EF.(ea,1)  via v_dot2_f32_f16
// logit = Lin[bh].(edge,1) + sum_c G'_c|u_c|;  p8[bh*EtotPad+i] = exp(logit)
__global__ __launch_bounds__(256) void logits_kernel(
    const uint4* __restrict__ eh4,
    const float* __restrict__ Lin,
    const uint4* __restrict__ pwD,
    float* __restrict__ p8, int EtotPad, int nchunks)
{
    int blk = blockIdx.x;
    int bh = blk / nchunks;          // phase-major: whole GPU sweeps one bh
    int chunk = blk - bh * nchunks;
    int t = threadIdx.x;
    int iA = chunk * 512 + t;
    int iB = iA + 256;
    uint4 eA = eh4[iA], eB = eh4[iB];
    v2h xsA = bch(eA.x), xdA = bch(eA.y), eaA = bch(eA.z);
    v2h xsB = bch(eB.x), xdB = bch(eB.y), eaB = bch(eB.z);

    const uint4* wp = pwD + bh * 128;   // 2KB slice, scalar-cache hot
    float a0 = 0.f, a1 = 0.f;
    #pragma unroll 8
    for (int c = 0; c < 128; ++c) {
        uint4 w = wp[c];                // uniform -> s_load_dwordx4
        v2h AB = bch(w.x), CD = bch(w.y), EF = bch(w.z);
        float G = __uint_as_float(w.w);
        float uA = FDOT2(AB, xsA, FDOT2(CD, xdA, FDOT2(EF, eaA, 0.f)));
        float uB = FDOT2(AB, xsB, FDOT2(CD, xdB, FDOT2(EF, eaB, 0.f)));
        a0 = fmaf(G, __builtin_fabsf(uA), a0);
        a1 = fmaf(G, __builtin_fabsf(uB), a1);
    }

    const float* Lp = Lin + bh * 6;     // uniform -> s_load
    float l0 = Lp[0], l1 = Lp[1], l2 = Lp[2], l3 = Lp[3], l4 = Lp[4], l5 = Lp[5];
    float lgA = fmaf(l0, (float)xsA.x, fmaf(l1, (float)xsA.y,
                fmaf(l2, (float)xdA.x, fmaf(l3, (float)xdA.y,
                fmaf(l4, (float)eaA.x, l5))))) + a0;
    float lgB = fmaf(l0, (float)xsB.x, fmaf(l1, (float)xsB.y,
                fmaf(l2, (float)xdB.x, fmaf(l3, (float)xdB.y,
                fmaf(l4, (float)eaB.x, l5))))) + a1;
    float* plane = p8 + (size_t)bh * EtotPad;
    plane[iA] = __expf(lgA);
    plane[iB] = __expf(lgB);
}

// ---------------- nodeS: per-node gather; stores S pre-divided by denom -----
__global__ __launch_bounds__(256) void nodeS_kernel(
    const int* __restrict__ rowptr, const float4* __restrict__ ed4,
    const float* __restrict__ p8, float* __restrict__ S, int N, int EtotPad)
{
    int t = threadIdx.x;
    int g = t >> 3, bh = t & 7;
    int n = blockIdx.x * 32 + g;
    if (n >= N) return;
    int beg = rowptr[n], end = rowptr[n + 1];
    const float* plane = p8 + (size_t)bh * EtotPad;
    float s0 = 0.f, s1 = 0.f, sb = 0.f;
    for (int i = beg; i < end; ++i) {
        float4 ed = ed4[i];
        float p = plane[i];
        s0 = fmaf(p, ed.x, s0);
        s1 = fmaf(p, ed.y, s1);
        sb += p;
    }
    float rin = 1.f / (sb + 1e-16f);
    float* Sp = S + (size_t)n * 24 + bh * 3;
    Sp[0] = s0 * rin;
    Sp[1] = s1 * rin;
    Sp[2] = sb * rin;
}

// ---------------- node: h-build (f32->bf16 LDS) + MFMA fuse GEMM ------------
__global__ __launch_bounds__(512) void node_kernel(
    const float* __restrict__ x,
    const float* __restrict__ S,
    const float* __restrict__ Wsrc0, const float* __restrict__ bsrc0,
    const float* __restrict__ bias0, const float* __restrict__ Wres0,
    const float* __restrict__ Wsrc1, const float* __restrict__ bsrc1,
    const float* __restrict__ bias1, const float* __restrict__ Wres1,
    const unsigned short* __restrict__ pwB, const float* __restrict__ bfuse,
    float* __restrict__ out, int N)
{
    __shared__ __align__(16) unsigned short hb[NPB][264];
    int t = threadIdx.x;
    int c = t & (CC - 1);
    int quarter = t >> 7;
    int n0 = blockIdx.x * NPB;

    float w00[HH], w01[HH], wb0[HH], w10[HH], w11[HH], wb1[HH];
    #pragma unroll
    for (int h = 0; h < HH; ++h) {
        w00[h] = Wsrc0[h * CC + c];
        w01[h] = Wsrc0[512 + h * CC + c];
        wb0[h] = bsrc0[h * CC + c];
        w10[h] = Wsrc1[h * CC + c];
        w11[h] = Wsrc1[512 + h * CC + c];
        wb1[h] = bsrc1[h * CC + c];
    }
    float bi0 = bias0[c], bi1 = bias1[c];
    float r00 = Wres0[c], r01 = Wres0[CC + c];
    float r10 = Wres1[c], r11 = Wres1[CC + c];

    for (int ni = quarter; ni < NPB; ni += 4) {
        int n = n0 + ni;
        if (n < N) {
            float x0 = x[2 * n], x1 = x[2 * n + 1];
            const float4* Sp4 = (const float4*)(S + (size_t)n * 24);
            float4 q0 = Sp4[0], q1 = Sp4[1], q2 = Sp4[2];
            float4 q3 = Sp4[3], q4 = Sp4[4], q5 = Sp4[5];
            float h0v, h1v;
            {
                float s0[HH] = {q0.x, q0.w, q1.z, q2.y};
                float s1[HH] = {q0.y, q1.x, q1.w, q2.z};
                float sb[HH] = {q0.z, q1.y, q2.x, q2.w};
                float acc = 0.f;
                #pragma unroll
                for (int h = 0; h < HH; ++h)
                    acc += fmaf(w00[h], s0[h], fmaf(w01[h], s1[h], wb0[h] * sb[h]));
                float o = fmaxf(acc * 0.25f + bi0, 0.f);
                h0v = o + x0 * r00 + x1 * r01;
            }
            {
                float s0[HH] = {q3.x, q3.w, q4.z, q5.y};
                float s1[HH] = {q3.y, q4.x, q4.w, q5.z};
                float sb[HH] = {q3.z, q4.y, q5.x, q5.w};
                float acc = 0.f;
                #pragma unroll
                for (int h = 0; h < HH; ++h)
                    acc += fmaf(w10[h], s0[h], fmaf(w11[h], s1[h], wb1[h] * sb[h]));
                float o = fmaxf(acc * 0.25f + bi1, 0.f);
                h1v = o + x0 * r10 + x1 * r11;
            }
            hb[ni][c] = f2bf(h0v);
            hb[ni][CC + c] = f2bf(h1v);
        }
    }
    __syncthreads();

    int w = t >> 6;
    int l = t & 63;
    int nt = w & 3;
    int cthalf = w >> 2;
    int row = nt * 16 + (l & 15);

    short8v a[8];
    #pragma unroll
    for (int kc = 0; kc < 8; ++kc)
        a[kc] = *reinterpret_cast<const short8v*>(&hb[row][kc * 32 + (l >> 4) * 8]);

    const short8v* pB = reinterpret_cast<const short8v*>(pwB);
    #pragma unroll
    for (int ci = 0; ci < 4; ++ci) {
        int ct = cthalf * 4 + ci;
        f32x4 acc = {0.f, 0.f, 0.f, 0.f};
        #pragma unroll
        for (int kc = 0; kc < 8; ++kc) {
            short8v b = pB[(ct * 8 + kc) * 64 + l];
            acc = __builtin_amdgcn_mfma_f32_16x16x32_bf16(a[kc], b, acc, 0, 0, 0);
        }
        int ch = ct * 16 + (l & 15);
        float bi = bfuse[ch];
        #pragma unroll
        for (int j = 0; j < 4; ++j) {
            int n = n0 + nt * 16 + (l >> 4) * 4 + j;
            if (n < N) out[(size_t)n * CC + ch] = fmaxf(acc[j] + bi, 0.f);
        }
    }
}

extern "C" void kernel_launch(void* const* d_in, const int* in_sizes, int n_in,
                              void* d_out, int out_size, void* d_ws, size_t ws_size,
                              hipStream_t stream) {
    const float* x      = (const float*)d_in[0];
    const int*   ei     = (const int*)d_in[1];
    const float* eattr  = (const float*)d_in[2];
    const float* Wsrc0  = (const float*)d_in[3];
    const float* bsrc0  = (const float*)d_in[4];
    const float* Wdst0  = (const float*)d_in[5];
    const float* bdst0  = (const float*)d_in[6];
    const float* Wedge0 = (const float*)d_in[7];
    const float* att0   = (const float*)d_in[8];
    const float* bias0  = (const float*)d_in[9];
    const float* Wres0  = (const float*)d_in[10];
    const float* Wsrc1  = (const float*)d_in[11];
    const float* bsrc1  = (const float*)d_in[12];
    const float* Wdst1  = (const float*)d_in[13];
    const float* bdst1  = (const float*)d_in[14];
    const float* Wedge1 = (const float*)d_in[15];
    const float* att1   = (const float*)d_in[16];
    const float* bias1  = (const float*)d_in[17];
    const float* Wres1  = (const float*)d_in[18];
    const float* Wfuse  = (const float*)d_in[19];
    const float* bfuse  = (const float*)d_in[20];
    float* out = (float*)d_out;

    int N = in_sizes[0] / 2;   // x is (N,2)
    int E = in_sizes[1] / 2;   // edge_index is (2,E)
    int Etot = E + N;
    int EtotPad = (Etot + 511) & ~511;

    // workspace layout; zero region = meansum(0..4) + cnt
    size_t off = 0;
    float* meansum = (float*)((char*)d_ws + off);  off += 256;
    int*   cnt     = (int*)((char*)d_ws + off);    off += roundup256((size_t)N * sizeof(int));
    size_t zero_bytes = off;
    float* Lin     = (float*)((char*)d_ws + off);  off += 256;
    int*   cur     = (int*)((char*)d_ws + off);    off += roundup256((size_t)N * sizeof(int));
    int*   rowptr  = (int*)((char*)d_ws + off);    off += roundup256((size_t)(N + 1) * sizeof(int));
    uint4* pwD     = (uint4*)((char*)d_ws + off);  off += roundup256(1024 * sizeof(uint4));
    unsigned short* pwB = (unsigned short*)((char*)d_ws + off);
                                                   off += roundup256(4096 * 8 * sizeof(unsigned short));
    float4* ed4    = (float4*)((char*)d_ws + off); off += roundup256((size_t)EtotPad * sizeof(float4));
    uint4* eh4     = (uint4*)((char*)d_ws + off);  off += roundup256((size_t)EtotPad * sizeof(uint4));
    float* p8      = (float*)((char*)d_ws + off);  off += roundup256((size_t)EtotPad * 8 * sizeof(float));
    float* S       = (float*)((char*)d_ws + off);  off += roundup256((size_t)24 * N * sizeof(float));

    hipMemsetAsync(d_ws, 0, zero_bytes, stream);

    prep_kernel<<<(E + 255) / 256, 256, 0, stream>>>(
        ei, eattr, meansum, Lin, cnt,
        Wsrc0, bsrc0, Wdst0, bdst0, Wedge0, att0,
        Wsrc1, bsrc1, Wdst1, bdst1, Wedge1, att1,
        Wfuse, pwD, pwB, E);

    scan_kernel<<<1, 1024, 0, stream>>>(cnt, rowptr, cur, N);

    scatter_kernel<<<(Etot + 255) / 256, 256, 0, stream>>>(
        ei, x, eattr, meansum, cur, ed4, eh4, N, E);

    int nchunks = EtotPad / 512;
    logits_kernel<<<8 * nchunks, 256, 0, stream>>>(
        eh4, Lin, pwD, p8, EtotPad, nchunks);

    nodeS_kernel<<<(N + 31) / 32, 256, 0, stream>>>(rowptr, ed4, p8, S, N, EtotPad);

    node_kernel<<<(N + NPB - 1) / NPB, 512, 0, stream>>>(
        x, S,
        Wsrc0, bsrc0, bias0, Wres0,
        Wsrc1, bsrc1, bias1, Wres1,
        pwB, bfuse, out, N);
}

// Round 17
// 175.047 us; speedup vs baseline: 1.1348x; 1.0429x over previous
//
#include <hip/hip_runtime.h>

#define HH 4
#define CC 128
#define NPB 64

typedef __attribute__((ext_vector_type(8))) short short8v;   // 8 bf16
typedef __attribute__((ext_vector_type(4))) float f32x4;
typedef _Float16 v2h __attribute__((ext_vector_type(2)));

static inline size_t roundup256(size_t x) { return (x + 255) & ~(size_t)255; }

static __device__ __forceinline__ unsigned short f2bf(float f) {
    unsigned int u = __float_as_uint(f);
    unsigned int r = (u + 0x7FFFu + ((u >> 16) & 1u)) >> 16;   // RNE
    return (unsigned short)r;
}
static __device__ __forceinline__ v2h bch(unsigned int u) {
    v2h r;
    __builtin_memcpy(&r, &u, 4);
    return r;
}
static __device__ __forceinline__ unsigned int pkh(float a, float b) {
    v2h h = {(_Float16)a, (_Float16)b};
    unsigned int u;
    __builtin_memcpy(&u, &h, 4);
    return u;
}
#if __has_builtin(__builtin_amdgcn_fdot2)
#define FDOT2(a, b, c) __builtin_amdgcn_fdot2((a), (b), (c), false)
#else
#define FDOT2(a, b, c) \
    fmaf((float)(a).x, (float)(b).x, fmaf((float)(a).y, (float)(b).y, (c)))
#endif

// ---------------- prep: mean + hist + Lin + pwD (dot2 weights) + pwB --------
// pwD[bh*128+c] = uint4{ pk(A,B), pk(C,D), pk(E,F), bits(0.4*att) }
// Lin[bh][6] = 0.6*sum_c att*{A,B,C,D,E,F}
// pwB[(ct*8+kc)*64+l][j] = bf16(Wfuse[kc*32+(l>>4)*8+j][ct*16+(l&15)])
__global__ __launch_bounds__(256) void prep_kernel(
    const int* __restrict__ ei, const float* __restrict__ eattr,
    float* __restrict__ meansum, float* __restrict__ Lin, int* __restrict__ cnt,
    const float* __restrict__ Wsrc0, const float* __restrict__ bsrc0,
    const float* __restrict__ Wdst0, const float* __restrict__ bdst0,
    const float* __restrict__ Wedge0, const float* __restrict__ att0,
    const float* __restrict__ Wsrc1, const float* __restrict__ bsrc1,
    const float* __restrict__ Wdst1, const float* __restrict__ bdst1,
    const float* __restrict__ Wedge1, const float* __restrict__ att1,
    const float* __restrict__ Wfuse,
    uint4* __restrict__ pwD, unsigned short* __restrict__ pwB, int E)
{
    int tid = blockIdx.x * 256 + threadIdx.x;
    int lane = threadIdx.x & 63, wid = threadIdx.x >> 6;
    float s = 0.f;
    if (tid < E) {
        atomicAdd(&cnt[ei[E + tid]], 1);
        s = eattr[tid];
    }
    #pragma unroll
    for (int off = 32; off > 0; off >>= 1) s += __shfl_down(s, off, 64);
    __shared__ float wsum[4];
    if (lane == 0) wsum[wid] = s;
    __syncthreads();
    if (threadIdx.x == 0)
        atomicAdd(meansum, wsum[0] + wsum[1] + wsum[2] + wsum[3]);

    if (blockIdx.x < 4) {  // tid < 1024: one thread per (b,h,c)
        int b = tid >> 9;
        int hc = tid & 511;
        int c = hc & 127;
        int h = hc >> 7;
        int bh = b * 4 + h;
        const float* Ws = b ? Wsrc1 : Wsrc0;
        const float* bs = b ? bsrc1 : bsrc0;
        const float* Wd = b ? Wdst1 : Wdst0;
        const float* bd = b ? bdst1 : bdst0;
        const float* We = b ? Wedge1 : Wedge0;
        const float* at = b ? att1 : att0;
        float A = Ws[hc], B = Ws[512 + hc];
        float C = Wd[hc], D = Wd[512 + hc];
        float Ec = We[hc];
        float F = bs[hc] + bd[hc];
        float a = at[hc];
        pwD[bh * 128 + c] = make_uint4(pkh(A, B), pkh(C, D), pkh(Ec, F),
                                       __float_as_uint(0.4f * a));
        float sa = 0.6f * a;
        float vals[6] = {sa * A, sa * B, sa * C, sa * D, sa * Ec, sa * F};
        #pragma unroll
        for (int k = 0; k < 6; ++k) {
            float v = vals[k];
            #pragma unroll
            for (int off = 32; off > 0; off >>= 1) v += __shfl_down(v, off, 64);
            vals[k] = v;
        }
        __shared__ float Ls[4][6];
        if (lane == 0) {
            #pragma unroll
            for (int k = 0; k < 6; ++k) Ls[wid][k] = vals[k];
        }
        __syncthreads();
        if (threadIdx.x < 12) {
            int w2 = threadIdx.x / 6;
            int k = threadIdx.x % 6;
            int bhg = blockIdx.x * 2 + w2;
            Lin[bhg * 6 + k] = Ls[w2 * 2][k] + Ls[w2 * 2 + 1][k];
        }
    }

    if (blockIdx.x >= 4 && blockIdx.x < 20) {  // Wfuse -> bf16 B-frags (node)
        int t2 = tid - 1024;                   // 0..4095
        int ct = t2 >> 9;
        int kc = (t2 >> 6) & 7;
        int l  = t2 & 63;
        int c = ct * 16 + (l & 15);
        int kb = kc * 32 + (l >> 4) * 8;
        unsigned short v[8];
        #pragma unroll
        for (int j = 0; j < 8; ++j)
            v[j] = f2bf(Wfuse[(kb + j) * CC + c]);
        unsigned short* dst = pwB + (size_t)t2 * 8;
        #pragma unroll
        for (int j = 0; j < 8; ++j) dst[j] = v[j];
    }
}

// ---------------- scan: exclusive prefix over (cnt+1), seeds cur ------------
__global__ __launch_bounds__(1024) void scan_kernel(const int* __restrict__ cnt,
                                                    int* __restrict__ rowptr,
                                                    int* __restrict__ cur, int N) {
    const int CH = 32;
    int t = threadIdx.x;
    int base = t * CH;
    int local[CH];
    int s = 0;
    #pragma unroll
    for (int i = 0; i < CH; ++i) {
        int idx = base + i;
        int v = (idx < N) ? cnt[idx] + 1 : 0;  // +1 = self loop
        local[i] = s;
        s += v;
    }
    __shared__ int sums[1024];
    sums[t] = s;
    __syncthreads();
    for (int off = 1; off < 1024; off <<= 1) {
        int v = (t >= off) ? sums[t - off] : 0;
        __syncthreads();
        sums[t] += v;
        __syncthreads();
    }
    int excl = sums[t] - s;
    #pragma unroll
    for (int i = 0; i < CH; ++i) {
        int idx = base + i;
        if (idx < N) {
            int v = excl + local[i];
            rowptr[idx] = v;
            cur[idx] = v;
        }
    }
    if (t == 1023) rowptr[N] = excl + s;
}

// ---------------- scatter: CSR edge record {pk(xs),pk(xd),pk(ea,1),src} -----
__global__ __launch_bounds__(256) void scatter_kernel(
    const int* __restrict__ ei, const float* __restrict__ x,
    const float* __restrict__ eattr, const float* __restrict__ meansum,
    int* __restrict__ cur, uint4* __restrict__ eh4, int N, int E) {
    int e = blockIdx.x * 256 + threadIdx.x;
    int Etot = E + N;
    if (e >= Etot) return;
    int src, dst;
    float ea;
    if (e < E) { src = ei[e]; dst = ei[E + e]; ea = eattr[e]; }
    else       { src = e - E; dst = src; ea = meansum[0] / (float)E; }
    int pos = atomicAdd(&cur[dst], 1);
    const float2* x2 = (const float2*)x;
    float2 xs = x2[src];
    float2 xd = x2[dst];
    eh4[pos] = make_uint4(pkh(xs.x, xs.y), pkh(xd.x, xd.y), pkh(ea, 1.f),
                          (unsigned)src);
}

// ---------------- logits: fp16 dot2, 2 bh per block, 2 edges/lane -----------
// u = AB.(xs0,xs1) + CD.(xd0,xd1) + EF.(ea,1)  via v_dot2_f32_f16
// logit = Lin[bh].(edge,1) + sum_c G'_c|u_c|;  p8[i*8+bh] = exp(logit)
__global__ __launch_bounds__(256) void logits_kernel(
    const uint4* __restrict__ eh4,
    const float* __restrict__ Lin,
    const uint4* __restrict__ pwD,
    float* __restrict__ p8, int nchunks)
{
    int blk = blockIdx.x;
    int bhp = blk / nchunks;         // 0..3 (bh pair); phase-major sweep
    int chunk = blk - bhp * nchunks;
    int t = threadIdx.x;
    int iA = chunk * 512 + t;
    int iB = iA + 256;
    uint4 eA = eh4[iA], eB = eh4[iB];
    v2h xsA = bch(eA.x), xdA = bch(eA.y), eaA = bch(eA.z);
    v2h xsB = bch(eB.x), xdB = bch(eB.y), eaB = bch(eB.z);

    #pragma unroll
    for (int bi = 0; bi < 2; ++bi) {
        int bh = bhp * 2 + bi;
        const uint4* wp = pwD + bh * 128;   // 2KB slice, scalar-cache hot
        float a0 = 0.f, a1 = 0.f;
        #pragma unroll 8
        for (int c = 0; c < 128; ++c) {
            uint4 w = wp[c];                // uniform -> s_load_dwordx4
            v2h AB = bch(w.x), CD = bch(w.y), EF = bch(w.z);
            float G = __uint_as_float(w.w);
            float uA = FDOT2(AB, xsA, FDOT2(CD, xdA, FDOT2(EF, eaA, 0.f)));
            float uB = FDOT2(AB, xsB, FDOT2(CD, xdB, FDOT2(EF, eaB, 0.f)));
            a0 = fmaf(G, __builtin_fabsf(uA), a0);
            a1 = fmaf(G, __builtin_fabsf(uB), a1);
        }
        const float* Lp = Lin + bh * 6;     // uniform -> s_load
        float l0 = Lp[0], l1 = Lp[1], l2 = Lp[2], l3 = Lp[3], l4 = Lp[4], l5 = Lp[5];
        float lgA = fmaf(l0, (float)xsA.x, fmaf(l1, (float)xsA.y,
                    fmaf(l2, (float)xdA.x, fmaf(l3, (float)xdA.y,
                    fmaf(l4, (float)eaA.x, l5))))) + a0;
        float lgB = fmaf(l0, (float)xsB.x, fmaf(l1, (float)xsB.y,
                    fmaf(l2, (float)xdB.x, fmaf(l3, (float)xdB.y,
                    fmaf(l4, (float)eaB.x, l5))))) + a1;
        p8[(size_t)iA * 8 + bh] = __expf(lgA);
        p8[(size_t)iB * 8 + bh] = __expf(lgB);
    }
}

// ---------------- node: gather (fused) + h-build + MFMA fuse GEMM -----------
// 512 threads, 64 nodes/block.
// phase0: 8 lanes/node gather over CSR; S -> LDS (pre-divided by denom)
// phase1: c=t&127, quarter=t>>7, h -> bf16 LDS
// phase2: 8 waves MFMA [64x256]x[256x128] + bias + ReLU
__global__ __launch_bounds__(512) void node_kernel(
    const float* __restrict__ x,
    const int* __restrict__ rowptr,
    const uint4* __restrict__ eh4,
    const float* __restrict__ p8,
    const float* __restrict__ Wsrc0, const float* __restrict__ bsrc0,
    const float* __restrict__ bias0, const float* __restrict__ Wres0,
    const float* __restrict__ Wsrc1, const float* __restrict__ bsrc1,
    const float* __restrict__ bias1, const float* __restrict__ Wres1,
    const unsigned short* __restrict__ pwB, const float* __restrict__ bfuse,
    float* __restrict__ out, int N)
{
    __shared__ __align__(16) unsigned short hb[NPB][264];  // 33 KB
    __shared__ __align__(16) float Sl[NPB][24];            // 6 KB
    int t = threadIdx.x;
    int n0 = blockIdx.x * NPB;
    const float2* x2 = (const float2*)x;

    // ---- phase 0: per-node gather (8 lanes = 8 bh per node) ----
    {
        int g = t >> 3, bh = t & 7;
        int n = n0 + g;
        if (n < N) {
            int beg = rowptr[n], end = rowptr[n + 1];
            float s0 = 0.f, s1 = 0.f, sb = 0.f;
            for (int i = beg; i < end; ++i) {
                float p = p8[(size_t)i * 8 + bh];   // 8 lanes: one 32B segment
                unsigned srcu = eh4[i].w;           // broadcast within group
                float2 xs = x2[srcu];               // L2-hot broadcast
                s0 = fmaf(p, xs.x, s0);
                s1 = fmaf(p, xs.y, s1);
                sb += p;
            }
            float rin = 1.f / (sb + 1e-16f);
            Sl[g][bh * 3 + 0] = s0 * rin;
            Sl[g][bh * 3 + 1] = s1 * rin;
            Sl[g][bh * 3 + 2] = sb * rin;
        }
    }
    __syncthreads();

    // ---- phase 1: h build ----
    int c = t & (CC - 1);
    int quarter = t >> 7;

    float w00[HH], w01[HH], wb0[HH], w10[HH], w11[HH], wb1[HH];
    #pragma unroll
    for (int h = 0; h < HH; ++h) {
        w00[h] = Wsrc0[h * CC + c];
        w01[h] = Wsrc0[512 + h * CC + c];
        wb0[h] = bsrc0[h * CC + c];
        w10[h] = Wsrc1[h * CC + c];
        w11[h] = Wsrc1[512 + h * CC + c];
        wb1[h] = bsrc1[h * CC + c];
    }
    float bi0 = bias0[c], bi1 = bias1[c];
    float r00 = Wres0[c], r01 = Wres0[CC + c];
    float r10 = Wres1[c], r11 = Wres1[CC + c];

    for (int ni = quarter; ni < NPB; ni += 4) {
        int n = n0 + ni;
        if (n < N) {
            float x0 = x[2 * n], x1 = x[2 * n + 1];
            const float4* Sp4 = (const float4*)&Sl[ni][0];  // LDS broadcast
            float4 q0 = Sp4[0], q1 = Sp4[1], q2 = Sp4[2];
            float4 q3 = Sp4[3], q4 = Sp4[4], q5 = Sp4[5];
            float h0v, h1v;
            {
                float s0[HH] = {q0.x, q0.w, q1.z, q2.y};
                float s1[HH] = {q0.y, q1.x, q1.w, q2.z};
                float sb[HH] = {q0.z, q1.y, q2.x, q2.w};
                float acc = 0.f;
                #pragma unroll
                for (int h = 0; h < HH; ++h)
                    acc += fmaf(w00[h], s0[h], fmaf(w01[h], s1[h], wb0[h] * sb[h]));
                float o = fmaxf(acc * 0.25f + bi0, 0.f);
                h0v = o + x0 * r00 + x1 * r01;
            }
            {
                float s0[HH] = {q3.x, q3.w, q4.z, q5.y};
                float s1[HH] = {q3.y, q4.x, q4.w, q5.z};
                float sb[HH] = {q3.z, q4.y, q5.x, q5.w};
                float acc = 0.f;
                #pragma unroll
                for (int h = 0; h < HH; ++h)
                    acc += fmaf(w10[h], s0[h], fmaf(w11[h], s1[h], wb1[h] * sb[h]));
                float o = fmaxf(acc * 0.25f + bi1, 0.f);
                h1v = o + x0 * r10 + x1 * r11;
            }
            hb[ni][c] = f2bf(h0v);
            hb[ni][CC + c] = f2bf(h1v);
        }
    }
    __syncthreads();

    // ---- phase 2: MFMA ----
    int w = t >> 6;
    int l = t & 63;
    int nt = w & 3;
    int cthalf = w >> 2;
    int row = nt * 16 + (l & 15);

    short8v a[8];
    #pragma unroll
    for (int kc = 0; kc < 8; ++kc)
        a[kc] = *reinterpret_cast<const short8v*>(&hb[row][kc * 32 + (l >> 4) * 8]);

    const short8v* pB = reinterpret_cast<const short8v*>(pwB);
    #pragma unroll
    for (int ci = 0; ci < 4; ++ci) {
        int ct = cthalf * 4 + ci;
        f32x4 acc = {0.f, 0.f, 0.f, 0.f};
        #pragma unroll
        for (int kc = 0; kc < 8; ++kc) {
            short8v b = pB[(ct * 8 + kc) * 64 + l];
            acc = __builtin_amdgcn_mfma_f32_16x16x32_bf16(a[kc], b, acc, 0, 0, 0);
        }
        int ch = ct * 16 + (l & 15);
        float bi = bfuse[ch];
        #pragma unroll
        for (int j = 0; j < 4; ++j) {
            int n = n0 + nt * 16 + (l >> 4) * 4 + j;
            if (n < N) out[(size_t)n * CC + ch] = fmaxf(acc[j] + bi, 0.f);
        }
    }
}

extern "C" void kernel_launch(void* const* d_in, const int* in_sizes, int n_in,
                              void* d_out, int out_size, void* d_ws, size_t ws_size,
                              hipStream_t stream) {
    const float* x      = (const float*)d_in[0];
    const int*   ei     = (const int*)d_in[1];
    const float* eattr  = (const float*)d_in[2];
    const float* Wsrc0  = (const float*)d_in[3];
    const float* bsrc0  = (const float*)d_in[4];
    const float* Wdst0  = (const float*)d_in[5];
    const float* bdst0  = (const float*)d_in[6];
    const float* Wedge0 = (const float*)d_in[7];
    const float* att0   = (const float*)d_in[8];
    const float* bias0  = (const float*)d_in[9];
    const float* Wres0  = (const float*)d_in[10];
    const float* Wsrc1  = (const float*)d_in[11];
    const float* bsrc1  = (const float*)d_in[12];
    const float* Wdst1  = (const float*)d_in[13];
    const float* bdst1  = (const float*)d_in[14];
    const float* Wedge1 = (const float*)d_in[15];
    const float* att1   = (const float*)d_in[16];
    const float* bias1  = (const float*)d_in[17];
    const float* Wres1  = (const float*)d_in[18];
    const float* Wfuse  = (const float*)d_in[19];
    const float* bfuse  = (const float*)d_in[20];
    float* out = (float*)d_out;

    int N = in_sizes[0] / 2;   // x is (N,2)
    int E = in_sizes[1] / 2;   // edge_index is (2,E)
    int Etot = E + N;
    int EtotPad = (Etot + 511) & ~511;

    // workspace layout; zero region = meansum(0..4) + cnt
    size_t off = 0;
    float* meansum = (float*)((char*)d_ws + off);  off += 256;
    int*   cnt     = (int*)((char*)d_ws + off);    off += roundup256((size_t)N * sizeof(int));
    size_t zero_bytes = off;
    float* Lin     = (float*)((char*)d_ws + off);  off += 256;
    int*   cur     = (int*)((char*)d_ws + off);    off += roundup256((size_t)N * sizeof(int));
    int*   rowptr  = (int*)((char*)d_ws + off);    off += roundup256((size_t)(N + 1) * sizeof(int));
    uint4* pwD     = (uint4*)((char*)d_ws + off);  off += roundup256(1024 * sizeof(uint4));
    unsigned short* pwB = (unsigned short*)((char*)d_ws + off);
                                                   off += roundup256(4096 * 8 * sizeof(unsigned short));
    uint4* eh4     = (uint4*)((char*)d_ws + off);  off += roundup256((size_t)EtotPad * sizeof(uint4));
    float* p8      = (float*)((char*)d_ws + off);  off += roundup256((size_t)EtotPad * 8 * sizeof(float));

    hipMemsetAsync(d_ws, 0, zero_bytes, stream);

    prep_kernel<<<(E + 255) / 256, 256, 0, stream>>>(
        ei, eattr, meansum, Lin, cnt,
        Wsrc0, bsrc0, Wdst0, bdst0, Wedge0, att0,
        Wsrc1, bsrc1, Wdst1, bdst1, Wedge1, att1,
        Wfuse, pwD, pwB, E);

    scan_kernel<<<1, 1024, 0, stream>>>(cnt, rowptr, cur, N);

    scatter_kernel<<<(Etot + 255) / 256, 256, 0, stream>>>(
        ei, x, eattr, meansum, cur, eh4, N, E);

    int nchunks = EtotPad / 512;
    logits_kernel<<<4 * nchunks, 256, 0, stream>>>(
        eh4, Lin, pwD, p8, nchunks);

    node_kernel<<<(N + NPB - 1) / NPB, 512, 0, stream>>>(
        x, rowptr, eh4, p8,
        Wsrc0, bsrc0, bias0, Wres0,
        Wsrc1, bsrc1, bias1, Wres1,
        pwB, bfuse, out, N);
}